// Round 5
// baseline (60477.063 us; speedup 1.0000x reference)
//
#include <hip/hip_runtime.h>
#include <hip/hip_bf16.h>
#include <math.h>

// DCSA block, round 5: round-4 naive diagnostic build with ONE change:
// final output written as FP32 (theory: d_out is fp32; bf16 writes were
// being read as packed halfwords -> bit-stable absmax 6.796875 across
// rounds 2/3/4). Inputs still runtime dtype-detected.

using bf16 = __hip_bfloat16;

static __device__ __forceinline__ float bf2f(bf16 x) { return __bfloat162float(x); }
static __device__ __forceinline__ bf16  f2b(float x) { return __float2bfloat16(x); }

static __device__ __forceinline__ float ldi(const void* p, size_t i, int isbf)
{
    return isbf ? bf2f(((const bf16*)p)[i]) : ((const float*)p)[i];
}

// ---------------------------------------------------------------------------
// Input dtype detection: lnq1_w is all-ones. bf16 1.0 -> ushort[0]==0x3F80.
// ---------------------------------------------------------------------------
__global__ void detect_kernel(const unsigned short* p, int* flag)
{
    if (threadIdx.x == 0 && blockIdx.x == 0)
        *flag = (p[0] == 0x3F80) ? 1 : 0;
}

// ---------------------------------------------------------------------------
// Naive conv KSxKS, pad PAD. One thread per output element.
// ---------------------------------------------------------------------------
template <int KS, int PAD>
__global__ void nconv(const void* __restrict__ In, const void* __restrict__ W,
                      const int* __restrict__ flagp, bf16* __restrict__ Y)
{
    int isbf = *flagp;
    int n  = blockIdx.x * 256 + threadIdx.x;
    int o  = blockIdx.y;
    int b  = blockIdx.z;
    int hh = n >> 5, ww = n & 31;
    float acc = 0.0f;
    for (int ci = 0; ci < 256; ++ci)
        for (int kh = 0; kh < KS; ++kh)
            for (int kw = 0; kw < KS; ++kw) {
                int hi = hh + kh - PAD, wi = ww + kw - PAD;
                if ((unsigned)hi < 32u && (unsigned)wi < 32u) {
                    float a = ldi(In, ((size_t)b * 256 + ci) * 1024 + hi * 32 + wi, isbf);
                    float w = ldi(W, (((size_t)o * 256 + ci) * KS + kh) * KS + kw, isbf);
                    acc = fmaf(a, w, acc);
                }
            }
    Y[((size_t)b * 256 + o) * 1024 + n] = f2b(acc);
}

// ---------------------------------------------------------------------------
// Naive GEMM: Y[b][o][n] = sum_i W[o][i]*X[b][i][n] (+R).
// If Yf != nullptr, write fp32 there instead of bf16 Y.
// ---------------------------------------------------------------------------
__global__ void ngemm(const void* __restrict__ W, const int* __restrict__ flagp,
                      const bf16* __restrict__ X, bf16* __restrict__ Y,
                      float* __restrict__ Yf,
                      const bf16* __restrict__ R, int O, int I)
{
    int isbf = *flagp;
    int n = blockIdx.x * 256 + threadIdx.x;
    int o = blockIdx.y;
    int b = blockIdx.z;
    const bf16* xp = X + (size_t)b * I * 1024 + n;
    float acc = 0.0f;
    for (int i = 0; i < I; ++i)
        acc = fmaf(ldi(W, (size_t)o * I + i, isbf), bf2f(xp[(size_t)i * 1024]), acc);
    size_t yo = ((size_t)b * O + o) * 1024 + n;
    if (R) acc += bf2f(R[yo]);
    if (Yf) Yf[yo] = acc;
    else    Y[yo]  = f2b(acc);
}

// ---------------------------------------------------------------------------
// Naive LayerNorm over 256 channels. One thread per pixel.
// ---------------------------------------------------------------------------
__global__ void nln(const bf16* __restrict__ X, const void* __restrict__ g,
                    const void* __restrict__ be, const int* __restrict__ flagp,
                    bf16* __restrict__ Y)
{
    int isbf = *flagp;
    int idx = blockIdx.x * 256 + threadIdx.x;
    int b = idx >> 10, px = idx & 1023;
    const bf16* xp = X + (size_t)b * 262144 + px;
    float s = 0.f, ss = 0.f;
    for (int c = 0; c < 256; ++c) {
        float v = bf2f(xp[(size_t)c * 1024]);
        s += v; ss += v * v;
    }
    float mu   = s * (1.0f / 256.0f);
    float var  = ss * (1.0f / 256.0f) - mu * mu;
    float rstd = rsqrtf(fmaxf(var, 0.0f) + 1e-5f);
    bf16* yp = Y + (size_t)b * 262144 + px;
    for (int c = 0; c < 256; ++c) {
        float v = bf2f(xp[(size_t)c * 1024]);
        yp[(size_t)c * 1024] = f2b((v - mu) * rstd * ldi(g, c, isbf) + ldi(be, c, isbf));
    }
}

// ---------------------------------------------------------------------------
// Naive attention. One thread per (b, head, query). Two passes over keys.
// ---------------------------------------------------------------------------
__global__ void nattn(const bf16* __restrict__ Q, const bf16* __restrict__ K,
                      const bf16* __restrict__ V, long long qbs, long long kvbs,
                      bf16* __restrict__ Out)
{
    int n = blockIdx.x * 64 + threadIdx.x;
    int h = blockIdx.y;
    int b = blockIdx.z;
    const bf16* Qb = Q + (size_t)b * qbs  + (size_t)h * 65536;
    const bf16* Kb = K + (size_t)b * kvbs + (size_t)h * 65536;
    const bf16* Vb = V + (size_t)b * kvbs + (size_t)h * 65536;

    float qc[64];
#pragma unroll
    for (int d = 0; d < 64; ++d) qc[d] = bf2f(Qb[(size_t)d * 1024 + n]);

    float mx = -1e30f;
    for (int m = 0; m < 1024; ++m) {
        float s = 0.f;
#pragma unroll
        for (int d = 0; d < 64; ++d) s = fmaf(qc[d], bf2f(Kb[(size_t)d * 1024 + m]), s);
        s *= 0.125f;
        mx = fmaxf(mx, s);
    }

    float den = 0.f;
    float num[64];
#pragma unroll
    for (int d = 0; d < 64; ++d) num[d] = 0.f;
    for (int m = 0; m < 1024; ++m) {
        float s = 0.f;
#pragma unroll
        for (int d = 0; d < 64; ++d) s = fmaf(qc[d], bf2f(Kb[(size_t)d * 1024 + m]), s);
        s *= 0.125f;
        float e = expf(s - mx);
        den += e;
#pragma unroll
        for (int d = 0; d < 64; ++d) num[d] = fmaf(e, bf2f(Vb[(size_t)d * 1024 + m]), num[d]);
    }

    float dinv = 1.0f / den;
    bf16* op = Out + (size_t)b * 262144 + (size_t)h * 65536 + n;
#pragma unroll
    for (int d = 0; d < 64; ++d) op[(size_t)d * 1024] = f2b(num[d] * dinv);
}

// ---------------------------------------------------------------------------
// Naive depthwise 3x3 + exact GELU.
// ---------------------------------------------------------------------------
__global__ void ndwgelu(const bf16* __restrict__ H, const void* __restrict__ Wdw,
                        const int* __restrict__ flagp, bf16* __restrict__ Y)
{
    int isbf = *flagp;
    int n = blockIdx.x * 256 + threadIdx.x;
    int c = blockIdx.y;
    int b = blockIdx.z;
    int hh = n >> 5, ww = n & 31;
    const bf16* hp = H + ((size_t)b * 1024 + c) * 1024;
    float acc = 0.0f;
#pragma unroll
    for (int kh = 0; kh < 3; ++kh)
#pragma unroll
        for (int kw = 0; kw < 3; ++kw) {
            int hi = hh + kh - 1, wi = ww + kw - 1;
            if ((unsigned)hi < 32u && (unsigned)wi < 32u)
                acc = fmaf(ldi(Wdw, (size_t)c * 9 + kh * 3 + kw, isbf),
                           bf2f(hp[hi * 32 + wi]), acc);
        }
    float gel = 0.5f * acc * (1.0f + erff(acc * 0.70710678118654752f));
    Y[(((size_t)b * 1024 + c) * 1024) + n] = f2b(gel);
}

// ---------------------------------------------------------------------------
extern "C" void kernel_launch(void* const* d_in, const int* in_sizes, int n_in,
                              void* d_out, int out_size, void* d_ws, size_t ws_size,
                              hipStream_t stream)
{
    int*  flag = (int*)d_ws;
    const size_t SZ = 2097152;                  // 8*256*1024 elements
    bf16* slab = (bf16*)((char*)d_ws + 256);
    bf16* qb  = slab + 0 * SZ;                  // q_branch -> x
    bf16* kvb = slab + 1 * SZ;
    bf16* t0  = slab + 2 * SZ;
    bf16* q   = slab + 3 * SZ;
    bf16* kv  = slab + 4 * SZ;
    bf16* D   = slab + 5 * SZ;                  // 3 slots (qkv / cross q,k,v)
    bf16* hb  = slab + 5 * SZ;                  // 4 slots, reuses dead D
    bf16* h2  = slab + 1 * SZ;                  // 4 slots, reuses dead kvb/t0/q/kv
    float* out = (float*)d_out;                 // <-- fp32 output (the fix)

    const long long QKV_BS = 786432, ONE_BS = 262144;
    dim3 b256(256), b64(64);

    detect_kernel<<<1, 64, 0, stream>>>((const unsigned short*)d_in[4], flag);

    // branches: conv3x3(aop) and conv5x5(dop)
    nconv<3, 1><<<dim3(4, 256, 8), b256, 0, stream>>>(d_in[0], d_in[2], flag, qb);
    nconv<5, 2><<<dim3(4, 256, 8), b256, 0, stream>>>(d_in[1], d_in[3], flag, kvb);

    // q branch self-attention
    nln<<<dim3(32), b256, 0, stream>>>(qb, d_in[4], d_in[5], flag, t0);
    ngemm<<<dim3(4, 768, 8), b256, 0, stream>>>(d_in[14], flag, t0, D, nullptr, nullptr, 768, 256);
    nattn<<<dim3(16, 4, 8), b64, 0, stream>>>(D, D + 262144, D + 524288, QKV_BS, QKV_BS, t0);
    ngemm<<<dim3(4, 256, 8), b256, 0, stream>>>(d_in[15], flag, t0, qb, nullptr, qb, 256, 256);
    nln<<<dim3(32), b256, 0, stream>>>(qb, d_in[8], d_in[9], flag, q);

    // kv branch self-attention
    nln<<<dim3(32), b256, 0, stream>>>(kvb, d_in[6], d_in[7], flag, t0);
    ngemm<<<dim3(4, 768, 8), b256, 0, stream>>>(d_in[16], flag, t0, D, nullptr, nullptr, 768, 256);
    nattn<<<dim3(16, 4, 8), b64, 0, stream>>>(D, D + 262144, D + 524288, QKV_BS, QKV_BS, t0);
    ngemm<<<dim3(4, 256, 8), b256, 0, stream>>>(d_in[17], flag, t0, kvb, nullptr, kvb, 256, 256);
    nln<<<dim3(32), b256, 0, stream>>>(kvb, d_in[10], d_in[11], flag, kv);

    // cross attention
    ngemm<<<dim3(4, 256, 8), b256, 0, stream>>>(d_in[18], flag, q,  D,          nullptr, nullptr, 256, 256);
    ngemm<<<dim3(4, 256, 8), b256, 0, stream>>>(d_in[19], flag, kv, D + SZ,     nullptr, nullptr, 256, 256);
    ngemm<<<dim3(4, 256, 8), b256, 0, stream>>>(d_in[20], flag, kv, D + 2 * SZ, nullptr, nullptr, 256, 256);
    nattn<<<dim3(16, 4, 8), b64, 0, stream>>>(D, D + SZ, D + 2 * SZ, ONE_BS, ONE_BS, t0);
    ngemm<<<dim3(4, 256, 8), b256, 0, stream>>>(d_in[21], flag, t0, qb, nullptr, qb, 256, 256);  // x

    // LeFF
    nln<<<dim3(32), b256, 0, stream>>>(qb, d_in[12], d_in[13], flag, t0);
    ngemm<<<dim3(4, 1024, 8), b256, 0, stream>>>(d_in[22], flag, t0, hb, nullptr, nullptr, 1024, 256);
    ndwgelu<<<dim3(4, 1024, 8), b256, 0, stream>>>(hb, d_in[23], flag, h2);
    // final: fp32 into d_out
    ngemm<<<dim3(4, 256, 8), b256, 0, stream>>>(d_in[24], flag, h2, nullptr, out, qb, 256, 1024);
}

// Round 6
// 1865.591 us; speedup vs baseline: 32.4171x; 32.4171x over previous
//
#include <hip/hip_runtime.h>
#include <hip/hip_bf16.h>

// DCSA block, round 6: round-3 tiled build (proven numerically correct by
// the bit-identical-output analysis) + the round-5 fix: d_out is FP32.
// Inputs runtime dtype-detected and staged to a canonical bf16 pool.

using bf16 = __hip_bfloat16;

static __device__ __forceinline__ float bf2f(bf16 x) { return __bfloat162float(x); }

// ---------------------------------------------------------------------------
// Input dtype detection: lnq1_w is all-ones. bf16 1.0 -> ushort[0]==0x3F80.
// ---------------------------------------------------------------------------
__global__ void detect_kernel(const unsigned short* p, int* flag)
{
    if (threadIdx.x == 0 && blockIdx.x == 0)
        *flag = (p[0] == 0x3F80) ? 1 : 0;
}

// ---------------------------------------------------------------------------
// Convert all inputs into canonical bf16 pool.
// ---------------------------------------------------------------------------
struct CvtArgs {
    const void* src[25];
    unsigned    off[26];
};

__global__ __launch_bounds__(256) void cvt_kernel(CvtArgs a, const int* __restrict__ flag,
                                                  bf16* __restrict__ dst)
{
    unsigned e = blockIdx.x * 256u + threadIdx.x;
    int isbf = *flag;
    int s = 0;
    while (e >= a.off[s + 1]) ++s;
    unsigned l = e - a.off[s];
    if (isbf) dst[e] = ((const bf16*)a.src[s])[l];
    else      dst[e] = __float2bfloat16(((const float*)a.src[s])[l]);
}

// ---------------------------------------------------------------------------
// GEMM: Y[b] = W[O,I] x X[b][I,1024] (+ optional residual R). bf16 in,
// fp32 accumulate; writes bf16 Y or fp32 Yf. 64x64 tile, 4x4 microtile.
// ---------------------------------------------------------------------------
__global__ __launch_bounds__(256) void gemm_kernel(
    const bf16* __restrict__ W, const bf16* __restrict__ X,
    bf16* __restrict__ Y, float* __restrict__ Yf,
    const bf16* __restrict__ R, int O, int I)
{
    const int N = 1024;
    int b  = blockIdx.z;
    int o0 = blockIdx.y * 64;
    int n0 = blockIdx.x * 64;
    const bf16* Xb = X + (size_t)b * I * N;

    __shared__ float As[16][68];   // [k][o]
    __shared__ float Bs[16][68];   // [k][n]

    int t  = threadIdx.x;
    int tx = t & 15, ty = t >> 4;
    int aoo = t >> 2, akk = (t & 3) * 4;
    int bkk = t >> 4, bnn = (t & 15) * 4;

    float acc[4][4] = {};

    for (int k0 = 0; k0 < I; k0 += 16) {
        const bf16* wp = W + (size_t)(o0 + aoo) * I + k0 + akk;
#pragma unroll
        for (int j = 0; j < 4; ++j) As[akk + j][aoo] = bf2f(wp[j]);
        const bf16* xp = Xb + (size_t)(k0 + bkk) * N + n0 + bnn;
#pragma unroll
        for (int j = 0; j < 4; ++j) Bs[bkk][bnn + j] = bf2f(xp[j]);
        __syncthreads();
#pragma unroll
        for (int kk = 0; kk < 16; ++kk) {
            float4 a = *(const float4*)&As[kk][ty * 4];
            float4 v = *(const float4*)&Bs[kk][tx * 4];
            float ar[4] = {a.x, a.y, a.z, a.w};
            float br[4] = {v.x, v.y, v.z, v.w};
#pragma unroll
            for (int i = 0; i < 4; ++i)
#pragma unroll
                for (int j = 0; j < 4; ++j)
                    acc[i][j] = fmaf(ar[i], br[j], acc[i][j]);
        }
        __syncthreads();
    }

    size_t yb = (size_t)b * O * N + (size_t)(o0 + ty * 4) * N + n0 + tx * 4;
#pragma unroll
    for (int i = 0; i < 4; ++i)
#pragma unroll
        for (int j = 0; j < 4; ++j) {
            size_t off = yb + (size_t)i * N + j;
            float v = acc[i][j];
            if (R) v += bf2f(R[off]);
            if (Yf) Yf[off] = v;
            else    Y[off]  = __float2bfloat16(v);
        }
}

// ---------------------------------------------------------------------------
// Conv KSxKS (pad PAD) as implicit GEMM over K = 256*KS*KS. bf16 in/out.
// ---------------------------------------------------------------------------
template <int KS, int PAD>
__global__ __launch_bounds__(256) void conv_kernel(
    const bf16* __restrict__ In, const bf16* __restrict__ W,
    bf16* __restrict__ Y)
{
    const int N = 1024, K = 256 * KS * KS;
    int b  = blockIdx.z;
    int o0 = blockIdx.y * 64;
    int n0 = blockIdx.x * 64;
    const bf16* Inb = In + (size_t)b * 256 * N;

    __shared__ float As[16][68];
    __shared__ float Bs[16][68];

    int t  = threadIdx.x;
    int tx = t & 15, ty = t >> 4;
    int aoo = t >> 2, akk = (t & 3) * 4;
    int bkk = t >> 4, bnn = (t & 15) * 4;

    float acc[4][4] = {};

    for (int k0 = 0; k0 < K; k0 += 16) {
        const bf16* wp = W + (size_t)(o0 + aoo) * K + k0 + akk;
#pragma unroll
        for (int j = 0; j < 4; ++j) As[akk + j][aoo] = bf2f(wp[j]);

        int k  = k0 + bkk;
        int ci = k / (KS * KS);
        int r  = k % (KS * KS);
        int kh = r / KS, kw = r % KS;
#pragma unroll
        for (int j = 0; j < 4; ++j) {
            int n  = n0 + bnn + j;
            int hh = n >> 5, ww = n & 31;
            int hi = hh + kh - PAD, wi = ww + kw - PAD;
            float v = 0.0f;
            if ((unsigned)hi < 32u && (unsigned)wi < 32u)
                v = bf2f(Inb[(size_t)ci * N + hi * 32 + wi]);
            Bs[bkk][bnn + j] = v;
        }
        __syncthreads();
#pragma unroll
        for (int kk = 0; kk < 16; ++kk) {
            float4 a = *(const float4*)&As[kk][ty * 4];
            float4 v = *(const float4*)&Bs[kk][tx * 4];
            float ar[4] = {a.x, a.y, a.z, a.w};
            float br[4] = {v.x, v.y, v.z, v.w};
#pragma unroll
            for (int i2 = 0; i2 < 4; ++i2)
#pragma unroll
                for (int j2 = 0; j2 < 4; ++j2)
                    acc[i2][j2] = fmaf(ar[i2], br[j2], acc[i2][j2]);
        }
        __syncthreads();
    }

    size_t yb = (size_t)b * 256 * N + (size_t)(o0 + ty * 4) * N + n0 + tx * 4;
#pragma unroll
    for (int i = 0; i < 4; ++i)
#pragma unroll
        for (int j = 0; j < 4; ++j)
            Y[yb + (size_t)i * N + j] = __float2bfloat16(acc[i][j]);
}

// ---------------------------------------------------------------------------
// LayerNorm over channel dim (C=256) of [B,256,1024] bf16.
// ---------------------------------------------------------------------------
__global__ __launch_bounds__(256) void ln_kernel(
    const bf16* __restrict__ X, const bf16* __restrict__ g,
    const bf16* __restrict__ be, bf16* __restrict__ Y)
{
    __shared__ float gs[256], bs[256];
    __shared__ float RA[4][64], RB[4][64];
    int t = threadIdx.x;
    gs[t] = bf2f(g[t]);
    bs[t] = bf2f(be[t]);
    int px = t & 63, part = t >> 6;
    size_t gid = (size_t)blockIdx.x * 64 + px;
    size_t base = (gid >> 10) * (size_t)256 * 1024 + (gid & 1023);
    const bf16* xp = X + base;
    float s = 0.f, ss = 0.f;
    for (int c = part * 64; c < part * 64 + 64; ++c) {
        float v = bf2f(xp[(size_t)c * 1024]);
        s += v; ss += v * v;
    }
    RA[part][px] = s; RB[part][px] = ss;
    __syncthreads();
    float st = 0.f, sst = 0.f;
#pragma unroll
    for (int p = 0; p < 4; ++p) { st += RA[p][px]; sst += RB[p][px]; }
    float mu   = st * (1.0f / 256.0f);
    float var  = sst * (1.0f / 256.0f) - mu * mu;
    float rstd = rsqrtf(fmaxf(var, 0.0f) + 1e-5f);
    bf16* yp = Y + base;
    for (int c = part * 64; c < part * 64 + 64; ++c) {
        float v = bf2f(xp[(size_t)c * 1024]);
        yp[(size_t)c * 1024] = __float2bfloat16((v - mu) * rstd * gs[c] + bs[c]);
    }
}

// ---------------------------------------------------------------------------
// Flash-style attention (bf16 I/O, fp32 compute). One block per
// (b, head, 64-query tile). LDS 57,088 B via Ks/Ps + RedM/RedS aliasing
// (race-free under the barrier structure; see round-3 notes).
// ---------------------------------------------------------------------------
__global__ __launch_bounds__(256) void attn_kernel(
    const bf16* __restrict__ Q, const bf16* __restrict__ K,
    const bf16* __restrict__ V, long long qbs, long long kvbs,
    bf16* __restrict__ Out)
{
    const int N = 1024;
    int b = blockIdx.z, h = blockIdx.y, n0 = blockIdx.x * 64;
    Q   += (size_t)b * qbs  + (size_t)h * 64 * N;
    K   += (size_t)b * kvbs + (size_t)h * 64 * N;
    V   += (size_t)b * kvbs + (size_t)h * 64 * N;
    Out += (size_t)b * 256 * N + (size_t)h * 64 * N;

    __shared__ float Qs[64][68];
    __shared__ float KsPs[64][68];
    __shared__ float Vs[64][68];
    __shared__ float RedMS[16][64];
    __shared__ float Mx[64], Lx[64], Al[64];

#define Ks   KsPs
#define Ps   KsPs
#define RedM RedMS
#define RedS RedMS

    int t = threadIdx.x;
    int tx = t & 15, ty = t >> 4;

    {
        int d = t >> 2, nb = (t & 3) * 16;
        const bf16* qp = Q + (size_t)d * N + n0 + nb;
#pragma unroll
        for (int j = 0; j < 16; ++j) Qs[d][nb + j] = bf2f(qp[j]);
    }
    if (t < 64) { Mx[t] = -1e30f; Lx[t] = 0.0f; }
    float acc[4][4] = {};
    __syncthreads();

    for (int m0 = 0; m0 < N; m0 += 64) {
        {
            int d = t >> 2, mb = (t & 3) * 16;
            const bf16* kp = K + (size_t)d * N + m0 + mb;
#pragma unroll
            for (int j = 0; j < 16; ++j) Ks[d][mb + j] = bf2f(kp[j]);
            const bf16* vp = V + (size_t)d * N + m0 + mb;
#pragma unroll
            for (int j = 0; j < 16; ++j) Vs[mb + j][d] = bf2f(vp[j]);
        }
        __syncthreads();

        float s[4][4] = {};
#pragma unroll
        for (int dd = 0; dd < 64; ++dd) {
            float4 a = *(const float4*)&Qs[dd][ty * 4];
            float4 v = *(const float4*)&Ks[dd][tx * 4];
            float ar[4] = {a.x, a.y, a.z, a.w};
            float br[4] = {v.x, v.y, v.z, v.w};
#pragma unroll
            for (int i = 0; i < 4; ++i)
#pragma unroll
                for (int j = 0; j < 4; ++j)
                    s[i][j] = fmaf(ar[i], br[j], s[i][j]);
        }
#pragma unroll
        for (int i = 0; i < 4; ++i)
#pragma unroll
            for (int j = 0; j < 4; ++j) s[i][j] *= 0.125f;

#pragma unroll
        for (int i = 0; i < 4; ++i)
            RedM[tx][ty * 4 + i] =
                fmaxf(fmaxf(s[i][0], s[i][1]), fmaxf(s[i][2], s[i][3]));
        __syncthreads();
        if (t < 64) {
            float rm = RedM[0][t];
#pragma unroll
            for (int p = 1; p < 16; ++p) rm = fmaxf(rm, RedM[p][t]);
            float mo = Mx[t], mn = fmaxf(mo, rm);
            float al = __expf(mo - mn);
            Mx[t] = mn; Al[t] = al; Lx[t] *= al;
        }
        __syncthreads();

        float aln[4];
#pragma unroll
        for (int j = 0; j < 4; ++j) aln[j] = Al[tx * 4 + j];
#pragma unroll
        for (int i = 0; i < 4; ++i)
#pragma unroll
            for (int j = 0; j < 4; ++j) acc[i][j] *= aln[j];

        float rowm[4];
#pragma unroll
        for (int i = 0; i < 4; ++i) rowm[i] = Mx[ty * 4 + i];
        float psum[4] = {};
#pragma unroll
        for (int i = 0; i < 4; ++i)
#pragma unroll
            for (int j = 0; j < 4; ++j) {
                float p = __expf(s[i][j] - rowm[i]);
                Ps[tx * 4 + j][ty * 4 + i] = p;
                psum[i] += p;
            }
#pragma unroll
        for (int i = 0; i < 4; ++i) RedS[tx][ty * 4 + i] = psum[i];
        __syncthreads();
        if (t < 64) {
            float ssum = 0.f;
#pragma unroll
            for (int p = 0; p < 16; ++p) ssum += RedS[p][t];
            Lx[t] += ssum;
        }

#pragma unroll
        for (int m = 0; m < 64; ++m) {
            float4 a = *(const float4*)&Vs[m][ty * 4];
            float4 v = *(const float4*)&Ps[m][tx * 4];
            float ar[4] = {a.x, a.y, a.z, a.w};
            float br[4] = {v.x, v.y, v.z, v.w};
#pragma unroll
            for (int i = 0; i < 4; ++i)
#pragma unroll
                for (int j = 0; j < 4; ++j)
                    acc[i][j] = fmaf(ar[i], br[j], acc[i][j]);
        }
        __syncthreads();
    }

    float linv[4];
#pragma unroll
    for (int j = 0; j < 4; ++j) linv[j] = 1.0f / Lx[tx * 4 + j];
#pragma unroll
    for (int i = 0; i < 4; ++i)
#pragma unroll
        for (int j = 0; j < 4; ++j)
            Out[(size_t)(ty * 4 + i) * N + n0 + tx * 4 + j] =
                __float2bfloat16(acc[i][j] * linv[j]);

#undef Ks
#undef Ps
#undef RedM
#undef RedS
}

// ---------------------------------------------------------------------------
// Depthwise 3x3 conv + exact GELU on [8,1024,32,32] bf16.
// ---------------------------------------------------------------------------
__global__ __launch_bounds__(256) void dwgelu_kernel(
    const bf16* __restrict__ H, const bf16* __restrict__ Wdw,
    bf16* __restrict__ Y)
{
    __shared__ float wsh[9];
    int idx = blockIdx.x * 256 + threadIdx.x;
    int c = (idx >> 10) & 1023;
    if (threadIdx.x < 9) wsh[threadIdx.x] = bf2f(Wdw[c * 9 + threadIdx.x]);
    __syncthreads();
    int w  = idx & 31, hh = (idx >> 5) & 31;
    size_t base = ((size_t)(idx >> 10)) << 10;
    float acc = 0.0f;
#pragma unroll
    for (int kh = 0; kh < 3; ++kh)
#pragma unroll
        for (int kw = 0; kw < 3; ++kw) {
            int hi = hh + kh - 1, wi = w + kw - 1;
            if ((unsigned)hi < 32u && (unsigned)wi < 32u)
                acc = fmaf(wsh[kh * 3 + kw], bf2f(H[base + hi * 32 + wi]), acc);
        }
    Y[idx] = __float2bfloat16(0.5f * acc * (1.0f + erff(acc * 0.70710678118654752f)));
}

// ---------------------------------------------------------------------------
extern "C" void kernel_launch(void* const* d_in, const int* in_sizes, int n_in,
                              void* d_out, int out_size, void* d_ws, size_t ws_size,
                              hipStream_t stream)
{
    static const unsigned sizes[25] = {
        2097152, 2097152, 589824, 1638400,
        256, 256, 256, 256, 256, 256, 256, 256, 256, 256,
        196608, 65536, 196608, 65536,
        65536, 65536, 65536, 65536,
        262144, 9216, 262144};

    CvtArgs args;
    unsigned pre[26]; pre[0] = 0;
    for (int i = 0; i < 25; ++i) { args.src[i] = d_in[i]; pre[i + 1] = pre[i] + sizes[i]; }
    for (int i = 0; i < 26; ++i) args.off[i] = pre[i];
    const unsigned total = pre[25];                 // 7,745,024

    int*  flag  = (int*)d_ws;
    bf16* canon = (bf16*)d_ws + 128;
    bf16* cp[25];
    for (int i = 0; i < 25; ++i) cp[i] = canon + pre[i];

    const size_t SZ = 2097152;
    bf16* slab = canon + total;
    bf16* qb  = slab + 0 * SZ;                      // q_branch -> x
    bf16* kvb = slab + 1 * SZ;
    bf16* t0  = slab + 2 * SZ;
    bf16* q   = slab + 3 * SZ;
    bf16* kv  = slab + 4 * SZ;
    bf16* D   = slab + 5 * SZ;                      // 3 slots
    bf16* hb  = slab + 5 * SZ;                      // 4 slots (reuses dead D)
    bf16* h2  = slab + 1 * SZ;                      // 4 slots (reuses dead kvb..kv)
    float* out = (float*)d_out;                     // fp32 output

    dim3 blk(256);
    const long long QKV_BS = 786432, ONE_BS = 262144;

    detect_kernel<<<1, 64, 0, stream>>>((const unsigned short*)d_in[4], flag);
    cvt_kernel<<<total / 256, blk, 0, stream>>>(args, flag, canon);

    conv_kernel<3, 1><<<dim3(16, 4, 8), blk, 0, stream>>>(cp[0], cp[2], qb);
    conv_kernel<5, 2><<<dim3(16, 4, 8), blk, 0, stream>>>(cp[1], cp[3], kvb);

    ln_kernel<<<dim3(128), blk, 0, stream>>>(qb, cp[4], cp[5], t0);
    gemm_kernel<<<dim3(16, 12, 8), blk, 0, stream>>>(cp[14], t0, D, nullptr, nullptr, 768, 256);
    attn_kernel<<<dim3(16, 4, 8), blk, 0, stream>>>(D, D + 262144, D + 524288, QKV_BS, QKV_BS, t0);
    gemm_kernel<<<dim3(16, 4, 8), blk, 0, stream>>>(cp[15], t0, qb, nullptr, qb, 256, 256);
    ln_kernel<<<dim3(128), blk, 0, stream>>>(qb, cp[8], cp[9], q);

    ln_kernel<<<dim3(128), blk, 0, stream>>>(kvb, cp[6], cp[7], t0);
    gemm_kernel<<<dim3(16, 12, 8), blk, 0, stream>>>(cp[16], t0, D, nullptr, nullptr, 768, 256);
    attn_kernel<<<dim3(16, 4, 8), blk, 0, stream>>>(D, D + 262144, D + 524288, QKV_BS, QKV_BS, t0);
    gemm_kernel<<<dim3(16, 4, 8), blk, 0, stream>>>(cp[17], t0, kvb, nullptr, kvb, 256, 256);
    ln_kernel<<<dim3(128), blk, 0, stream>>>(kvb, cp[10], cp[11], kv);

    gemm_kernel<<<dim3(16, 4, 8), blk, 0, stream>>>(cp[18], q,  D,          nullptr, nullptr, 256, 256);
    gemm_kernel<<<dim3(16, 4, 8), blk, 0, stream>>>(cp[19], kv, D + SZ,     nullptr, nullptr, 256, 256);
    gemm_kernel<<<dim3(16, 4, 8), blk, 0, stream>>>(cp[20], kv, D + 2 * SZ, nullptr, nullptr, 256, 256);
    attn_kernel<<<dim3(16, 4, 8), blk, 0, stream>>>(D, D + SZ, D + 2 * SZ, ONE_BS, ONE_BS, t0);
    gemm_kernel<<<dim3(16, 4, 8), blk, 0, stream>>>(cp[21], t0, qb, nullptr, qb, 256, 256);

    ln_kernel<<<dim3(128), blk, 0, stream>>>(qb, cp[12], cp[13], t0);
    gemm_kernel<<<dim3(16, 16, 8), blk, 0, stream>>>(cp[22], t0, hb, nullptr, nullptr, 1024, 256);
    dwgelu_kernel<<<dim3(32768), blk, 0, stream>>>(hb, cp[23], h2);
    gemm_kernel<<<dim3(16, 4, 8), blk, 0, stream>>>(cp[24], h2, nullptr, out, qb, 256, 1024);
}

// Round 7
// 977.752 us; speedup vs baseline: 61.8532x; 1.9080x over previous
//
#include <hip/hip_runtime.h>
#include <hip/hip_bf16.h>

// DCSA block, round 7: bf16 MFMA port of conv + all GEMMs, NHWC activations.
// Attention stays on the proven fp32-VALU flash kernel (CHW qkv inputs,
// NHWC output) -- MFMA attention is the next round's change.

using bf16 = __hip_bfloat16;
typedef short v8s __attribute__((ext_vector_type(8)));
typedef float v4f  __attribute__((ext_vector_type(4)));

static __device__ __forceinline__ float bf2f(bf16 x) { return __bfloat162float(x); }
static __device__ __forceinline__ float us2f(unsigned short u)
{ union { unsigned int i; float f; } x; x.i = ((unsigned)u) << 16; return x.f; }
static __device__ __forceinline__ unsigned short f2us(float f)
{ bf16 h = __float2bfloat16(f); return *(unsigned short*)&h; }
static __device__ __forceinline__ float ldi(const void* p, size_t i, int isbf)
{ return isbf ? bf2f(((const bf16*)p)[i]) : ((const float*)p)[i]; }

// ---------------------------------------------------------------------------
__global__ void detect_kernel(const unsigned short* p, int* flag)
{
    if (threadIdx.x == 0 && blockIdx.x == 0)
        *flag = (p[0] == 0x3F80) ? 1 : 0;
}

// ---------------------------------------------------------------------------
// Linear convert of weight/param inputs into canonical bf16 pool.
// ---------------------------------------------------------------------------
struct CvtArgs { const void* src[20]; unsigned off[21]; };

__global__ __launch_bounds__(256) void cvt_lin(CvtArgs a, const int* __restrict__ flag,
                                               bf16* __restrict__ dst)
{
    unsigned e = blockIdx.x * 256u + threadIdx.x;
    int isbf = *flag;
    int s = 0;
    while (e >= a.off[s + 1]) ++s;
    dst[e] = __float2bfloat16(ldi(a.src[s], e - a.off[s], isbf));
}

// ---------------------------------------------------------------------------
// CHW [b][256][1024] (raw dtype) -> NHWC [b*1024][256] bf16, LDS transpose.
// grid (16 hw-tiles, 4 c-tiles, 8 b), block 256.
// ---------------------------------------------------------------------------
__global__ __launch_bounds__(256) void tcvt(const void* __restrict__ src,
                                            const int* __restrict__ flag,
                                            bf16* __restrict__ dst)
{
    __shared__ float T[64][65];
    int hw0 = blockIdx.x * 64, c0 = blockIdx.y * 64, b = blockIdx.z;
    int t = threadIdx.x, isbf = *flag;
    int c = t >> 2, x16 = (t & 3) * 16;
    size_t sbase = ((size_t)b * 256 + c0 + c) * 1024 + hw0 + x16;
#pragma unroll
    for (int j = 0; j < 16; ++j) T[c][x16 + j] = ldi(src, sbase + j, isbf);
    __syncthreads();
    int hw = t >> 2, c16 = (t & 3) * 16;
    bf16* dp = dst + ((size_t)(b << 10) + hw0 + hw) * 256 + c0 + c16;
#pragma unroll
    for (int j = 0; j < 16; ++j) dp[j] = __float2bfloat16(T[c16 + j][hw]);
}

// ---------------------------------------------------------------------------
// Conv weight repack: W[o][ci][kh][kw] (raw) -> Wr[khkw][o][ci] bf16.
// ---------------------------------------------------------------------------
template <int KS>
__global__ __launch_bounds__(256) void repack_conv(const void* __restrict__ W,
                                                   const int* __restrict__ flag,
                                                   bf16* __restrict__ Wr)
{
    int idx = blockIdx.x * 256 + threadIdx.x;
    int isbf = *flag;
    int ci = idx & 255, o = (idx >> 8) & 255, khkw = idx >> 16;
    int kh = khkw / KS, kw = khkw % KS;
    Wr[idx] = __float2bfloat16(
        ldi(W, (((size_t)o * 256 + ci) * KS + kh) * KS + kw, isbf));
}

// dw weights: W[c][3][3] -> Wr[tap][c], c=1024.
__global__ __launch_bounds__(256) void repack_dw(const void* __restrict__ W,
                                                 const int* __restrict__ flag,
                                                 bf16* __restrict__ Wr)
{
    int idx = blockIdx.x * 256 + threadIdx.x;
    int isbf = *flag;
    int c = idx & 1023, tap = idx >> 10;
    Wr[idx] = __float2bfloat16(ldi(W, (size_t)c * 9 + tap, isbf));
}

// ---------------------------------------------------------------------------
// MFMA GEMM. MA: [M][K] bf16 rows (k-contig), MB: [N][K] bf16 rows (k-contig).
// D[m][n] = sum_k MA[m][k] MB[n][k]. grid (M/64, N/64), block 256 (4 waves).
// mode 0: m=pixel, n=o -> Yb NHWC [m*Ochan+n] (+R same layout)
// mode 1: m=o, n=pixel -> Yb CHW  [b][Ochan][1024]
// mode 2: m=o, n=pixel -> Yf CHW fp32, + R NHWC[p*256+o]
// ---------------------------------------------------------------------------
__global__ __launch_bounds__(256) void mgemm(
    const short* __restrict__ MA, const short* __restrict__ MB,
    bf16* __restrict__ Yb, float* __restrict__ Yf,
    const bf16* __restrict__ R, int K, int mode, int Ochan)
{
    __shared__ short As[64][40], Bs[64][40];
    int m0 = blockIdx.x * 64, n0 = blockIdx.y * 64;
    int t = threadIdx.x, lane = t & 63, wv = t >> 6;
    int l15 = lane & 15, quad = lane >> 4;
    int m_off = (wv & 1) * 32, n_off = (wv >> 1) * 32;
    int srow = t >> 2, scol = (t & 3) * 8;

    v4f acc[2][2] = {};

    for (int k0 = 0; k0 < K; k0 += 32) {
        *(v8s*)&As[srow][scol] = *(const v8s*)&MA[(size_t)(m0 + srow) * K + k0 + scol];
        *(v8s*)&Bs[srow][scol] = *(const v8s*)&MB[(size_t)(n0 + srow) * K + k0 + scol];
        __syncthreads();
        v8s a0 = *(const v8s*)&As[m_off + l15][quad * 8];
        v8s a1 = *(const v8s*)&As[m_off + 16 + l15][quad * 8];
        v8s b0 = *(const v8s*)&Bs[n_off + l15][quad * 8];
        v8s b1 = *(const v8s*)&Bs[n_off + 16 + l15][quad * 8];
        acc[0][0] = __builtin_amdgcn_mfma_f32_16x16x32_bf16(a0, b0, acc[0][0], 0, 0, 0);
        acc[0][1] = __builtin_amdgcn_mfma_f32_16x16x32_bf16(a0, b1, acc[0][1], 0, 0, 0);
        acc[1][0] = __builtin_amdgcn_mfma_f32_16x16x32_bf16(a1, b0, acc[1][0], 0, 0, 0);
        acc[1][1] = __builtin_amdgcn_mfma_f32_16x16x32_bf16(a1, b1, acc[1][1], 0, 0, 0);
        __syncthreads();
    }

#pragma unroll
    for (int mi = 0; mi < 2; ++mi)
#pragma unroll
        for (int ni = 0; ni < 2; ++ni)
#pragma unroll
            for (int r = 0; r < 4; ++r) {
                int mm = m0 + m_off + mi * 16 + quad * 4 + r;
                int nn = n0 + n_off + ni * 16 + l15;
                float v = acc[mi][ni][r];
                if (mode == 0) {
                    size_t off = (size_t)mm * Ochan + nn;
                    if (R) v += bf2f(R[off]);
                    Yb[off] = __float2bfloat16(v);
                } else {
                    int o = mm, p = nn;
                    size_t off = ((size_t)(p >> 10) * Ochan + o) * 1024 + (p & 1023);
                    if (mode == 1) Yb[off] = __float2bfloat16(v);
                    else           Yf[off] = v + bf2f(R[(size_t)p * 256 + o]);
                }
            }
}

// ---------------------------------------------------------------------------
// MFMA conv KSxKS (pad PAD), implicit GEMM over k=(khkw)*256+ci.
// Xn: NHWC [8192][256]; Wr: [khkw][o][ci]; Y: NHWC [8192][256].
// grid (128 pixel-tiles, 4 o-tiles), block 256.
// ---------------------------------------------------------------------------
template <int KS, int PAD>
__global__ __launch_bounds__(256) void mconv(
    const short* __restrict__ Xn, const short* __restrict__ Wr,
    bf16* __restrict__ Y)
{
    const int K = 256 * KS * KS;
    __shared__ short As[64][40], Bs[64][40];
    int p0 = blockIdx.x * 64, o0 = blockIdx.y * 64;
    int t = threadIdx.x, lane = t & 63, wv = t >> 6;
    int l15 = lane & 15, quad = lane >> 4;
    int m_off = (wv & 1) * 32, n_off = (wv >> 1) * 32;
    int srow = t >> 2, scol = (t & 3) * 8;

    int p  = p0 + srow;
    int hw = p & 1023, hh = hw >> 5, ww = hw & 31;
    size_t ib = ((size_t)(p >> 10)) << 10;

    v4f acc[2][2] = {};

    for (int k0 = 0; k0 < K; k0 += 32) {
        int khkw = k0 >> 8, ci = (k0 & 255) + scol;
        int kh = khkw / KS, kw = khkw % KS;
        int hi = hh + kh - PAD, wi = ww + kw - PAD;
        v8s av = {0, 0, 0, 0, 0, 0, 0, 0};
        if ((unsigned)hi < 32u && (unsigned)wi < 32u)
            av = *(const v8s*)&Xn[(ib + (hi << 5) + wi) * 256 + ci];
        *(v8s*)&As[srow][scol] = av;
        *(v8s*)&Bs[srow][scol] =
            *(const v8s*)&Wr[((size_t)khkw * 256 + o0 + srow) * 256 + ci];
        __syncthreads();
        v8s a0 = *(const v8s*)&As[m_off + l15][quad * 8];
        v8s a1 = *(const v8s*)&As[m_off + 16 + l15][quad * 8];
        v8s b0 = *(const v8s*)&Bs[n_off + l15][quad * 8];
        v8s b1 = *(const v8s*)&Bs[n_off + 16 + l15][quad * 8];
        acc[0][0] = __builtin_amdgcn_mfma_f32_16x16x32_bf16(a0, b0, acc[0][0], 0, 0, 0);
        acc[0][1] = __builtin_amdgcn_mfma_f32_16x16x32_bf16(a0, b1, acc[0][1], 0, 0, 0);
        acc[1][0] = __builtin_amdgcn_mfma_f32_16x16x32_bf16(a1, b0, acc[1][0], 0, 0, 0);
        acc[1][1] = __builtin_amdgcn_mfma_f32_16x16x32_bf16(a1, b1, acc[1][1], 0, 0, 0);
        __syncthreads();
    }

#pragma unroll
    for (int mi = 0; mi < 2; ++mi)
#pragma unroll
        for (int ni = 0; ni < 2; ++ni)
#pragma unroll
            for (int r = 0; r < 4; ++r) {
                int pp = p0 + m_off + mi * 16 + quad * 4 + r;
                int oo = o0 + n_off + ni * 16 + l15;
                Y[(size_t)pp * 256 + oo] = __float2bfloat16(acc[mi][ni][r]);
            }
}

// ---------------------------------------------------------------------------
// LayerNorm NHWC: one wave per pixel, lane covers 4 contiguous channels.
// grid 2048, block 256.
// ---------------------------------------------------------------------------
__global__ __launch_bounds__(256) void ln_nhwc(
    const bf16* __restrict__ X, const bf16* __restrict__ g,
    const bf16* __restrict__ be, bf16* __restrict__ Y)
{
    int wv = threadIdx.x >> 6, lane = threadIdx.x & 63;
    size_t p = (size_t)blockIdx.x * 4 + wv;
    const ushort4 u = *(const ushort4*)(X + p * 256 + lane * 4);
    float v0 = us2f(u.x), v1 = us2f(u.y), v2 = us2f(u.z), v3 = us2f(u.w);
    float s = v0 + v1 + v2 + v3;
    float ss = v0 * v0 + v1 * v1 + v2 * v2 + v3 * v3;
#pragma unroll
    for (int off = 32; off; off >>= 1) {
        s  += __shfl_xor(s, off);
        ss += __shfl_xor(ss, off);
    }
    float mu   = s * (1.0f / 256.0f);
    float var  = ss * (1.0f / 256.0f) - mu * mu;
    float rstd = rsqrtf(fmaxf(var, 0.0f) + 1e-5f);
    const ushort4 gu = *(const ushort4*)((const unsigned short*)g + lane * 4);
    const ushort4 bu = *(const ushort4*)((const unsigned short*)be + lane * 4);
    ushort4 o;
    o.x = f2us((v0 - mu) * rstd * us2f(gu.x) + us2f(bu.x));
    o.y = f2us((v1 - mu) * rstd * us2f(gu.y) + us2f(bu.y));
    o.z = f2us((v2 - mu) * rstd * us2f(gu.z) + us2f(bu.z));
    o.w = f2us((v3 - mu) * rstd * us2f(gu.w) + us2f(bu.w));
    *(ushort4*)(Y + p * 256 + lane * 4) = o;
}

// ---------------------------------------------------------------------------
// Flash attention (round-6 verified kernel). Q,K,V: CHW bf16 [d][1024] rows.
// Out: NHWC [8192][256] (only the write addressing changed vs round 6).
// ---------------------------------------------------------------------------
__global__ __launch_bounds__(256) void attn_kernel(
    const bf16* __restrict__ Q, const bf16* __restrict__ K,
    const bf16* __restrict__ V, long long qbs, long long kvbs,
    bf16* __restrict__ Out)
{
    const int N = 1024;
    int b = blockIdx.z, h = blockIdx.y, n0 = blockIdx.x * 64;
    Q += (size_t)b * qbs  + (size_t)h * 64 * N;
    K += (size_t)b * kvbs + (size_t)h * 64 * N;
    V += (size_t)b * kvbs + (size_t)h * 64 * N;

    __shared__ float Qs[64][68];
    __shared__ float KsPs[64][68];
    __shared__ float Vs[64][68];
    __shared__ float RedMS[16][64];
    __shared__ float Mx[64], Lx[64], Al[64];

#define Ks   KsPs
#define Ps   KsPs
#define RedM RedMS
#define RedS RedMS

    int t = threadIdx.x;
    int tx = t & 15, ty = t >> 4;

    {
        int d = t >> 2, nb = (t & 3) * 16;
        const bf16* qp = Q + (size_t)d * N + n0 + nb;
#pragma unroll
        for (int j = 0; j < 16; ++j) Qs[d][nb + j] = bf2f(qp[j]);
    }
    if (t < 64) { Mx[t] = -1e30f; Lx[t] = 0.0f; }
    float acc[4][4] = {};
    __syncthreads();

    for (int m0 = 0; m0 < N; m0 += 64) {
        {
            int d = t >> 2, mb = (t & 3) * 16;
            const bf16* kp = K + (size_t)d * N + m0 + mb;
#pragma unroll
            for (int j = 0; j < 16; ++j) Ks[d][mb + j] = bf2f(kp[j]);
            const bf16* vp = V + (size_t)d * N + m0 + mb;
#pragma unroll
            for (int j = 0; j < 16; ++j) Vs[mb + j][d] = bf2f(vp[j]);
        }
        __syncthreads();

        float s[4][4] = {};
#pragma unroll
        for (int dd = 0; dd < 64; ++dd) {
            float4 a = *(const float4*)&Qs[dd][ty * 4];
            float4 v = *(const float4*)&Ks[dd][tx * 4];
            float ar[4] = {a.x, a.y, a.z, a.w};
            float br[4] = {v.x, v.y, v.z, v.w};
#pragma unroll
            for (int i = 0; i < 4; ++i)
#pragma unroll
                for (int j = 0; j < 4; ++j)
                    s[i][j] = fmaf(ar[i], br[j], s[i][j]);
        }
#pragma unroll
        for (int i = 0; i < 4; ++i)
#pragma unroll
            for (int j = 0; j < 4; ++j) s[i][j] *= 0.125f;

#pragma unroll
        for (int i = 0; i < 4; ++i)
            RedM[tx][ty * 4 + i] =
                fmaxf(fmaxf(s[i][0], s[i][1]), fmaxf(s[i][2], s[i][3]));
        __syncthreads();
        if (t < 64) {
            float rm = RedM[0][t];
#pragma unroll
            for (int p = 1; p < 16; ++p) rm = fmaxf(rm, RedM[p][t]);
            float mo = Mx[t], mn = fmaxf(mo, rm);
            float al = __expf(mo - mn);
            Mx[t] = mn; Al[t] = al; Lx[t] *= al;
        }
        __syncthreads();

        float aln[4];
#pragma unroll
        for (int j = 0; j < 4; ++j) aln[j] = Al[tx * 4 + j];
#pragma unroll
        for (int i = 0; i < 4; ++i)
#pragma unroll
            for (int j = 0; j < 4; ++j) acc[i][j] *= aln[j];

        float rowm[4];
#pragma unroll
        for (int i = 0; i < 4; ++i) rowm[i] = Mx[ty * 4 + i];
        float psum[4] = {};
#pragma unroll
        for (int i = 0; i < 4; ++i)
#pragma unroll
            for (int j = 0; j < 4; ++j) {
                float pv = __expf(s[i][j] - rowm[i]);
                Ps[tx * 4 + j][ty * 4 + i] = pv;
                psum[i] += pv;
            }
#pragma unroll
        for (int i = 0; i < 4; ++i) RedS[tx][ty * 4 + i] = psum[i];
        __syncthreads();
        if (t < 64) {
            float ssum = 0.f;
#pragma unroll
            for (int p = 0; p < 16; ++p) ssum += RedS[p][t];
            Lx[t] += ssum;
        }

#pragma unroll
        for (int m = 0; m < 64; ++m) {
            float4 a = *(const float4*)&Vs[m][ty * 4];
            float4 v = *(const float4*)&Ps[m][tx * 4];
            float ar[4] = {a.x, a.y, a.z, a.w};
            float br[4] = {v.x, v.y, v.z, v.w};
#pragma unroll
            for (int i = 0; i < 4; ++i)
#pragma unroll
                for (int j = 0; j < 4; ++j)
                    acc[i][j] = fmaf(ar[i], br[j], acc[i][j]);
        }
        __syncthreads();
    }

    float linv[4];
#pragma unroll
    for (int j = 0; j < 4; ++j) linv[j] = 1.0f / Lx[tx * 4 + j];
    size_t ob = ((size_t)(b << 10)) * 256 + (size_t)h * 64;
#pragma unroll
    for (int i = 0; i < 4; ++i)
#pragma unroll
        for (int j = 0; j < 4; ++j)
            Out[ob + (size_t)(n0 + tx * 4 + j) * 256 + ty * 4 + i] =
                __float2bfloat16(acc[i][j] * linv[j]);

#undef Ks
#undef Ps
#undef RedM
#undef RedS
}

// ---------------------------------------------------------------------------
// Depthwise 3x3 + exact GELU, NHWC [8192][1024]. 8 channels/thread.
// grid 4096, block 256.
// ---------------------------------------------------------------------------
__global__ __launch_bounds__(256) void dwgelu_nhwc(
    const bf16* __restrict__ H, const bf16* __restrict__ Wr,
    bf16* __restrict__ Y)
{
    int idx = blockIdx.x * 256 + threadIdx.x;
    int p = idx >> 7, c8 = (idx & 127) * 8;
    int hw = p & 1023, hh = hw >> 5, ww = hw & 31;
    size_t ib = ((size_t)(p >> 10)) << 10;
    float acc[8] = {};
#pragma unroll
    for (int kh = 0; kh < 3; ++kh)
#pragma unroll
        for (int kw = 0; kw < 3; ++kw) {
            int hi = hh + kh - 1, wi = ww + kw - 1;
            if ((unsigned)hi < 32u && (unsigned)wi < 32u) {
                v8s hv = *(const v8s*)((const short*)H + (ib + (hi << 5) + wi) * 1024 + c8);
                v8s wv = *(const v8s*)((const short*)Wr + (kh * 3 + kw) * 1024 + c8);
#pragma unroll
                for (int j = 0; j < 8; ++j)
                    acc[j] = fmaf(us2f((unsigned short)wv[j]),
                                  us2f((unsigned short)hv[j]), acc[j]);
            }
        }
    short ov[8];
#pragma unroll
    for (int j = 0; j < 8; ++j) {
        float x = acc[j];
        ov[j] = (short)f2us(0.5f * x * (1.0f + erff(x * 0.70710678118654752f)));
    }
    v8s o = {ov[0], ov[1], ov[2], ov[3], ov[4], ov[5], ov[6], ov[7]};
    *(v8s*)((short*)Y + (size_t)p * 1024 + c8) = o;
}

// ---------------------------------------------------------------------------
extern "C" void kernel_launch(void* const* d_in, const int* in_sizes, int n_in,
                              void* d_out, int out_size, void* d_ws, size_t ws_size,
                              hipStream_t stream)
{
    // linear-staged inputs (weights/params), original indices:
    static const int  lidx[20] = {4,5,6,7,8,9,10,11,12,13,14,15,16,17,18,19,20,21,22,24};
    static const unsigned lsz[20] = {256,256,256,256,256,256,256,256,256,256,
                                     196608,65536,196608,65536,
                                     65536,65536,65536,65536,262144,262144};
    CvtArgs args;
    unsigned pre[21]; pre[0] = 0;
    for (int i = 0; i < 20; ++i) {
        args.src[i] = d_in[lidx[i]];
        pre[i + 1] = pre[i] + lsz[i];
    }
    for (int i = 0; i < 21; ++i) args.off[i] = pre[i];
    const unsigned ltot = pre[20];                 // 1,313,280 (= 5130*256)

    int*  flag  = (int*)d_ws;
    bf16* canon = (bf16*)d_ws + 128;
    bf16* cn[25];
    for (int i = 0; i < 20; ++i) cn[lidx[i]] = canon + pre[i];

    bf16* Wr3  = canon + ltot;                     // 589,824
    bf16* Wr5  = Wr3 + 589824;                     // 1,638,400
    bf16* Wdwr = Wr5 + 1638400;                    // 9,216
    const size_t SZ = 2097152;                     // one [8192][256] slab
    bf16* slab = Wdwr + 9216;
    bf16* qb   = slab + 0 * SZ;                    // q_branch -> x (NHWC)
    bf16* kvb  = slab + 1 * SZ;
    bf16* t0   = slab + 2 * SZ;
    bf16* q    = slab + 3 * SZ;
    bf16* kv   = slab + 4 * SZ;
    bf16* D    = slab + 5 * SZ;                    // 3 slots, CHW qkv
    bf16* hb   = slab + 5 * SZ;                    // 4 slots (reuses dead D)
    bf16* h2   = slab + 1 * SZ;                    // 4 slots (reuses kvb..kv)
    bf16* aopT = kvb;                              // dead before kvb written
    bf16* dopT = t0;                               // dead before t0 written
    float* out = (float*)d_out;
    // ws use ~44.9 MB

    dim3 blk(256);
    const long long QKV_BS = 786432, ONE_BS = 262144;
    const short* sWr3  = (const short*)Wr3;
    const short* sWr5  = (const short*)Wr5;
    auto S = [](const bf16* p) { return (const short*)p; };

    detect_kernel<<<1, 64, 0, stream>>>((const unsigned short*)d_in[4], flag);
    cvt_lin<<<ltot / 256, blk, 0, stream>>>(args, flag, canon);
    tcvt<<<dim3(16, 4, 8), blk, 0, stream>>>(d_in[0], flag, aopT);
    tcvt<<<dim3(16, 4, 8), blk, 0, stream>>>(d_in[1], flag, dopT);
    repack_conv<3><<<2304, blk, 0, stream>>>(d_in[2], flag, Wr3);
    repack_conv<5><<<6400, blk, 0, stream>>>(d_in[3], flag, Wr5);
    repack_dw<<<36, blk, 0, stream>>>(d_in[23], flag, Wdwr);

    // branches
    mconv<3, 1><<<dim3(128, 4), blk, 0, stream>>>(S(aopT), sWr3, qb);
    mconv<5, 2><<<dim3(128, 4), blk, 0, stream>>>(S(dopT), sWr5, kvb);

    // q-branch self-attention
    ln_nhwc<<<2048, blk, 0, stream>>>(qb, cn[4], cn[5], t0);
    mgemm<<<dim3(12, 128), blk, 0, stream>>>(S(cn[14]), S(t0), D, nullptr, nullptr, 256, 1, 768);
    attn_kernel<<<dim3(16, 4, 8), blk, 0, stream>>>(D, D + 262144, D + 524288, QKV_BS, QKV_BS, t0);
    mgemm<<<dim3(128, 4), blk, 0, stream>>>(S(t0), S(cn[15]), qb, nullptr, qb, 256, 0, 256);
    ln_nhwc<<<2048, blk, 0, stream>>>(qb, cn[8], cn[9], q);

    // kv-branch self-attention
    ln_nhwc<<<2048, blk, 0, stream>>>(kvb, cn[6], cn[7], t0);
    mgemm<<<dim3(12, 128), blk, 0, stream>>>(S(cn[16]), S(t0), D, nullptr, nullptr, 256, 1, 768);
    attn_kernel<<<dim3(16, 4, 8), blk, 0, stream>>>(D, D + 262144, D + 524288, QKV_BS, QKV_BS, t0);
    mgemm<<<dim3(128, 4), blk, 0, stream>>>(S(t0), S(cn[17]), kvb, nullptr, kvb, 256, 0, 256);
    ln_nhwc<<<2048, blk, 0, stream>>>(kvb, cn[10], cn[11], kv);

    // cross attention
    mgemm<<<dim3(4, 128), blk, 0, stream>>>(S(cn[18]), S(q),  D,          nullptr, nullptr, 256, 1, 256);
    mgemm<<<dim3(4, 128), blk, 0, stream>>>(S(cn[19]), S(kv), D + SZ,     nullptr, nullptr, 256, 1, 256);
    mgemm<<<dim3(4, 128), blk, 0, stream>>>(S(cn[20]), S(kv), D + 2 * SZ, nullptr, nullptr, 256, 1, 256);
    attn_kernel<<<dim3(16, 4, 8), blk, 0, stream>>>(D, D + SZ, D + 2 * SZ, ONE_BS, ONE_BS, t0);
    mgemm<<<dim3(128, 4), blk, 0, stream>>>(S(t0), S(cn[21]), qb, nullptr, qb, 256, 0, 256);

    // LeFF
    ln_nhwc<<<2048, blk, 0, stream>>>(qb, cn[12], cn[13], t0);
    mgemm<<<dim3(128, 16), blk, 0, stream>>>(S(t0), S(cn[22]), hb, nullptr, nullptr, 256, 0, 1024);
    dwgelu_nhwc<<<4096, blk, 0, stream>>>(hb, Wdwr, h2);
    mgemm<<<dim3(4, 128), blk, 0, stream>>>(S(cn[24]), S(h2), nullptr, out, qb, 1024, 2, 256);
}

// Round 8
// 633.404 us; speedup vs baseline: 95.4794x; 1.5436x over previous
//
#include <hip/hip_runtime.h>
#include <hip/hip_bf16.h>

// DCSA block, round 8: MFMA attention. Q,K in NHWC [8192][512] (d-contig),
// V in CHW (m-contig) so all MFMA fragments are direct 16B loads; P goes
// through a per-wave LDS transpose. K-loop is barrier-free (wave-local
// softmax). Conv/GEMM/LN/dwgelu identical to round 7 (verified).

using bf16 = __hip_bfloat16;
typedef short v8s __attribute__((ext_vector_type(8)));
typedef float v4f  __attribute__((ext_vector_type(4)));

static __device__ __forceinline__ float bf2f(bf16 x) { return __bfloat162float(x); }
static __device__ __forceinline__ float us2f(unsigned short u)
{ union { unsigned int i; float f; } x; x.i = ((unsigned)u) << 16; return x.f; }
static __device__ __forceinline__ unsigned short f2us(float f)
{ bf16 h = __float2bfloat16(f); return *(unsigned short*)&h; }
static __device__ __forceinline__ float ldi(const void* p, size_t i, int isbf)
{ return isbf ? bf2f(((const bf16*)p)[i]) : ((const float*)p)[i]; }

// ---------------------------------------------------------------------------
__global__ void detect_kernel(const unsigned short* p, int* flag)
{
    if (threadIdx.x == 0 && blockIdx.x == 0)
        *flag = (p[0] == 0x3F80) ? 1 : 0;
}

// ---------------------------------------------------------------------------
struct CvtArgs { const void* src[20]; unsigned off[21]; };

__global__ __launch_bounds__(256) void cvt_lin(CvtArgs a, const int* __restrict__ flag,
                                               bf16* __restrict__ dst)
{
    unsigned e = blockIdx.x * 256u + threadIdx.x;
    int isbf = *flag;
    int s = 0;
    while (e >= a.off[s + 1]) ++s;
    dst[e] = __float2bfloat16(ldi(a.src[s], e - a.off[s], isbf));
}

// ---------------------------------------------------------------------------
// CHW [b][256][1024] (raw dtype) -> NHWC [b*1024][256] bf16.
// ---------------------------------------------------------------------------
__global__ __launch_bounds__(256) void tcvt(const void* __restrict__ src,
                                            const int* __restrict__ flag,
                                            bf16* __restrict__ dst)
{
    __shared__ float T[64][65];
    int hw0 = blockIdx.x * 64, c0 = blockIdx.y * 64, b = blockIdx.z;
    int t = threadIdx.x, isbf = *flag;
    int c = t >> 2, x16 = (t & 3) * 16;
    size_t sbase = ((size_t)b * 256 + c0 + c) * 1024 + hw0 + x16;
#pragma unroll
    for (int j = 0; j < 16; ++j) T[c][x16 + j] = ldi(src, sbase + j, isbf);
    __syncthreads();
    int hw = t >> 2, c16 = (t & 3) * 16;
    bf16* dp = dst + ((size_t)(b << 10) + hw0 + hw) * 256 + c0 + c16;
#pragma unroll
    for (int j = 0; j < 16; ++j) dp[j] = __float2bfloat16(T[c16 + j][hw]);
}

// ---------------------------------------------------------------------------
template <int KS>
__global__ __launch_bounds__(256) void repack_conv(const void* __restrict__ W,
                                                   const int* __restrict__ flag,
                                                   bf16* __restrict__ Wr)
{
    int idx = blockIdx.x * 256 + threadIdx.x;
    int isbf = *flag;
    int ci = idx & 255, o = (idx >> 8) & 255, khkw = idx >> 16;
    int kh = khkw / KS, kw = khkw % KS;
    Wr[idx] = __float2bfloat16(
        ldi(W, (((size_t)o * 256 + ci) * KS + kh) * KS + kw, isbf));
}

__global__ __launch_bounds__(256) void repack_dw(const void* __restrict__ W,
                                                 const int* __restrict__ flag,
                                                 bf16* __restrict__ Wr)
{
    int idx = blockIdx.x * 256 + threadIdx.x;
    int isbf = *flag;
    int c = idx & 1023, tap = idx >> 10;
    Wr[idx] = __float2bfloat16(ldi(W, (size_t)c * 9 + tap, isbf));
}

// ---------------------------------------------------------------------------
// MFMA GEMM. MA:[M][K], MB:[N][K] (k-contig). D[m][n] = sum_k MA[m][k]MB[n][k].
// modes (m,n meaning / output):
//  0: m=pixel, n=o  -> Yb NHWC [m*Ochan+n] (+R)
//  1: m=o, n=pixel  -> Yb CHW [b][Ochan][1024]
//  2: m=o, n=pixel  -> Yf CHW fp32 + R NHWC[p*256+o]
//  3: m=o(768), n=p -> o<512: Yb(QK)[p*512+o]; o>=512: Y2(V) CHW 256ch
//  4: m=o(256), n=p -> Yb(QK)[p*512 + Ochan + o]   (Ochan = column offset)
// ---------------------------------------------------------------------------
__global__ __launch_bounds__(256) void mgemm(
    const short* __restrict__ MA, const short* __restrict__ MB,
    bf16* __restrict__ Yb, float* __restrict__ Yf, bf16* __restrict__ Y2,
    const bf16* __restrict__ R, int K, int mode, int Ochan)
{
    __shared__ short As[64][40], Bs[64][40];
    int m0 = blockIdx.x * 64, n0 = blockIdx.y * 64;
    int t = threadIdx.x, lane = t & 63, wv = t >> 6;
    int l15 = lane & 15, quad = lane >> 4;
    int m_off = (wv & 1) * 32, n_off = (wv >> 1) * 32;
    int srow = t >> 2, scol = (t & 3) * 8;

    v4f acc[2][2] = {};

    for (int k0 = 0; k0 < K; k0 += 32) {
        *(v8s*)&As[srow][scol] = *(const v8s*)&MA[(size_t)(m0 + srow) * K + k0 + scol];
        *(v8s*)&Bs[srow][scol] = *(const v8s*)&MB[(size_t)(n0 + srow) * K + k0 + scol];
        __syncthreads();
        v8s a0 = *(const v8s*)&As[m_off + l15][quad * 8];
        v8s a1 = *(const v8s*)&As[m_off + 16 + l15][quad * 8];
        v8s b0 = *(const v8s*)&Bs[n_off + l15][quad * 8];
        v8s b1 = *(const v8s*)&Bs[n_off + 16 + l15][quad * 8];
        acc[0][0] = __builtin_amdgcn_mfma_f32_16x16x32_bf16(a0, b0, acc[0][0], 0, 0, 0);
        acc[0][1] = __builtin_amdgcn_mfma_f32_16x16x32_bf16(a0, b1, acc[0][1], 0, 0, 0);
        acc[1][0] = __builtin_amdgcn_mfma_f32_16x16x32_bf16(a1, b0, acc[1][0], 0, 0, 0);
        acc[1][1] = __builtin_amdgcn_mfma_f32_16x16x32_bf16(a1, b1, acc[1][1], 0, 0, 0);
        __syncthreads();
    }

#pragma unroll
    for (int mi = 0; mi < 2; ++mi)
#pragma unroll
        for (int ni = 0; ni < 2; ++ni)
#pragma unroll
            for (int r = 0; r < 4; ++r) {
                int mm = m0 + m_off + mi * 16 + quad * 4 + r;
                int nn = n0 + n_off + ni * 16 + l15;
                float v = acc[mi][ni][r];
                if (mode == 0) {
                    size_t off = (size_t)mm * Ochan + nn;
                    if (R) v += bf2f(R[off]);
                    Yb[off] = __float2bfloat16(v);
                } else if (mode == 1) {
                    Yb[((size_t)(nn >> 10) * Ochan + mm) * 1024 + (nn & 1023)] =
                        __float2bfloat16(v);
                } else if (mode == 2) {
                    Yf[((size_t)(nn >> 10) * Ochan + mm) * 1024 + (nn & 1023)] =
                        v + bf2f(R[(size_t)nn * 256 + mm]);
                } else if (mode == 3) {
                    if (mm < 512) Yb[(size_t)nn * 512 + mm] = __float2bfloat16(v);
                    else Y2[((size_t)(nn >> 10) * 256 + (mm - 512)) * 1024 + (nn & 1023)] =
                             __float2bfloat16(v);
                } else {
                    Yb[(size_t)nn * 512 + Ochan + mm] = __float2bfloat16(v);
                }
            }
}

// ---------------------------------------------------------------------------
// MFMA conv (unchanged from round 7).
// ---------------------------------------------------------------------------
template <int KS, int PAD>
__global__ __launch_bounds__(256) void mconv(
    const short* __restrict__ Xn, const short* __restrict__ Wr,
    bf16* __restrict__ Y)
{
    const int K = 256 * KS * KS;
    __shared__ short As[64][40], Bs[64][40];
    int p0 = blockIdx.x * 64, o0 = blockIdx.y * 64;
    int t = threadIdx.x, lane = t & 63, wv = t >> 6;
    int l15 = lane & 15, quad = lane >> 4;
    int m_off = (wv & 1) * 32, n_off = (wv >> 1) * 32;
    int srow = t >> 2, scol = (t & 3) * 8;

    int p  = p0 + srow;
    int hw = p & 1023, hh = hw >> 5, ww = hw & 31;
    size_t ib = ((size_t)(p >> 10)) << 10;

    v4f acc[2][2] = {};

    for (int k0 = 0; k0 < K; k0 += 32) {
        int khkw = k0 >> 8, ci = (k0 & 255) + scol;
        int kh = khkw / KS, kw = khkw % KS;
        int hi = hh + kh - PAD, wi = ww + kw - PAD;
        v8s av = {0, 0, 0, 0, 0, 0, 0, 0};
        if ((unsigned)hi < 32u && (unsigned)wi < 32u)
            av = *(const v8s*)&Xn[(ib + (hi << 5) + wi) * 256 + ci];
        *(v8s*)&As[srow][scol] = av;
        *(v8s*)&Bs[srow][scol] =
            *(const v8s*)&Wr[((size_t)khkw * 256 + o0 + srow) * 256 + ci];
        __syncthreads();
        v8s a0 = *(const v8s*)&As[m_off + l15][quad * 8];
        v8s a1 = *(const v8s*)&As[m_off + 16 + l15][quad * 8];
        v8s b0 = *(const v8s*)&Bs[n_off + l15][quad * 8];
        v8s b1 = *(const v8s*)&Bs[n_off + 16 + l15][quad * 8];
        acc[0][0] = __builtin_amdgcn_mfma_f32_16x16x32_bf16(a0, b0, acc[0][0], 0, 0, 0);
        acc[0][1] = __builtin_amdgcn_mfma_f32_16x16x32_bf16(a0, b1, acc[0][1], 0, 0, 0);
        acc[1][0] = __builtin_amdgcn_mfma_f32_16x16x32_bf16(a1, b0, acc[1][0], 0, 0, 0);
        acc[1][1] = __builtin_amdgcn_mfma_f32_16x16x32_bf16(a1, b1, acc[1][1], 0, 0, 0);
        __syncthreads();
    }

#pragma unroll
    for (int mi = 0; mi < 2; ++mi)
#pragma unroll
        for (int ni = 0; ni < 2; ++ni)
#pragma unroll
            for (int r = 0; r < 4; ++r) {
                int pp = p0 + m_off + mi * 16 + quad * 4 + r;
                int oo = o0 + n_off + ni * 16 + l15;
                Y[(size_t)pp * 256 + oo] = __float2bfloat16(acc[mi][ni][r]);
            }
}

// ---------------------------------------------------------------------------
// MFMA flash attention. One block = (b, head, 64-query tile); wave w owns
// queries n0+w*16..+16 and ALL keys -> wave-local softmax, no barriers.
// QK: [8192][512] NHWC (Q at col h*64, K at col 256+h*64).
// V : CHW [8][256][1024], head rows h*64.. (m-contiguous).
// Out: NHWC [8192][256] at col h*64.
// ---------------------------------------------------------------------------
__global__ __launch_bounds__(256) void attn_mfma(
    const bf16* __restrict__ QK, const bf16* __restrict__ V,
    bf16* __restrict__ Out)
{
    int b = blockIdx.z, h = blockIdx.y, n0 = blockIdx.x * 64;
    int t = threadIdx.x, lane = t & 63, wv = t >> 6;
    int l15 = lane & 15, quad = lane >> 4;

    __shared__ short Ps[4][16][72];   // per-wave P^T staging (16B-aligned rows)

    const short* qk = (const short*)QK;
    const short* vp = (const short*)V + ((size_t)b * 256 + h * 64) * 1024;

    // Q fragments (constant over key loop): A-row l15 = query n0+wv*16+l15
    size_t qrow = ((size_t)b * 1024 + n0 + wv * 16 + l15) * 512 + h * 64;
    v8s qf0 = *(const v8s*)&qk[qrow + quad * 8];
    v8s qf1 = *(const v8s*)&qk[qrow + 32 + quad * 8];

    v4f oacc[4] = {};
    float mi[4], li[4];
#pragma unroll
    for (int r = 0; r < 4; ++r) { mi[r] = -1e30f; li[r] = 0.f; }
    const float LOG2E = 1.4426950408889634f;

    for (int m0 = 0; m0 < 1024; m0 += 64) {
        // S[q][k]: 4 col-tiles of 16 keys, K-dim d=64 (2 chained mfma)
        v4f sacc[4];
#pragma unroll
        for (int ct = 0; ct < 4; ++ct) {
            size_t krow = ((size_t)b * 1024 + m0 + ct * 16 + l15) * 512 + 256 + h * 64;
            v8s kf0 = *(const v8s*)&qk[krow + quad * 8];
            v8s kf1 = *(const v8s*)&qk[krow + 32 + quad * 8];
            v4f z = {0.f, 0.f, 0.f, 0.f};
            z = __builtin_amdgcn_mfma_f32_16x16x32_bf16(qf0, kf0, z, 0, 0, 0);
            z = __builtin_amdgcn_mfma_f32_16x16x32_bf16(qf1, kf1, z, 0, 0, 0);
            sacc[ct] = z;
        }

        // row max (rows quad*4+r), reduce across the 16 l15 lanes
        float rmax[4];
#pragma unroll
        for (int r = 0; r < 4; ++r)
            rmax[r] = 0.125f * fmaxf(fmaxf(sacc[0][r], sacc[1][r]),
                                     fmaxf(sacc[2][r], sacc[3][r]));
#pragma unroll
        for (int mk = 1; mk <= 8; mk <<= 1)
#pragma unroll
            for (int r = 0; r < 4; ++r)
                rmax[r] = fmaxf(rmax[r], __shfl_xor(rmax[r], mk));

        float al[4];
#pragma unroll
        for (int r = 0; r < 4; ++r) {
            float mn = fmaxf(mi[r], rmax[r]);
            al[r] = exp2f((mi[r] - mn) * LOG2E);
            mi[r] = mn;
        }

        // P = exp(s*scale - m); stage P^T rows into per-wave LDS
        float psum[4] = {};
#pragma unroll
        for (int ct = 0; ct < 4; ++ct)
#pragma unroll
            for (int r = 0; r < 4; ++r) {
                float pvv = exp2f((sacc[ct][r] * 0.125f - mi[r]) * LOG2E);
                psum[r] += pvv;
                Ps[wv][quad * 4 + r][ct * 16 + l15] = (short)f2us(pvv);
            }
#pragma unroll
        for (int mk = 1; mk <= 8; mk <<= 1)
#pragma unroll
            for (int r = 0; r < 4; ++r)
                psum[r] += __shfl_xor(psum[r], mk);
#pragma unroll
        for (int r = 0; r < 4; ++r) {
            li[r] = li[r] * al[r] + psum[r];
#pragma unroll
            for (int dt = 0; dt < 4; ++dt) oacc[dt][r] *= al[r];
        }

        // O += P V ; MA = P rows (l15=query, key-contig), MB = V rows (d, m-contig)
        v8s pf0 = *(const v8s*)&Ps[wv][l15][quad * 8];
        v8s pf1 = *(const v8s*)&Ps[wv][l15][32 + quad * 8];
#pragma unroll
        for (int dt = 0; dt < 4; ++dt) {
            const short* vr = vp + (size_t)(dt * 16 + l15) * 1024 + m0;
            v8s vf0 = *(const v8s*)&vr[quad * 8];
            v8s vf1 = *(const v8s*)&vr[32 + quad * 8];
            oacc[dt] = __builtin_amdgcn_mfma_f32_16x16x32_bf16(pf0, vf0, oacc[dt], 0, 0, 0);
            oacc[dt] = __builtin_amdgcn_mfma_f32_16x16x32_bf16(pf1, vf1, oacc[dt], 0, 0, 0);
        }
    }

    float linv[4];
#pragma unroll
    for (int r = 0; r < 4; ++r) linv[r] = 1.0f / li[r];
    size_t pb = (size_t)b * 1024 + n0 + wv * 16;
#pragma unroll
    for (int dt = 0; dt < 4; ++dt)
#pragma unroll
        for (int r = 0; r < 4; ++r)
            Out[(pb + quad * 4 + r) * 256 + h * 64 + dt * 16 + l15] =
                __float2bfloat16(oacc[dt][r] * linv[r]);
}

// ---------------------------------------------------------------------------
// LayerNorm NHWC (unchanged).
// ---------------------------------------------------------------------------
__global__ __launch_bounds__(256) void ln_nhwc(
    const bf16* __restrict__ X, const bf16* __restrict__ g,
    const bf16* __restrict__ be, bf16* __restrict__ Y)
{
    int wv = threadIdx.x >> 6, lane = threadIdx.x & 63;
    size_t p = (size_t)blockIdx.x * 4 + wv;
    const ushort4 u = *(const ushort4*)(X + p * 256 + lane * 4);
    float v0 = us2f(u.x), v1 = us2f(u.y), v2 = us2f(u.z), v3 = us2f(u.w);
    float s = v0 + v1 + v2 + v3;
    float ss = v0 * v0 + v1 * v1 + v2 * v2 + v3 * v3;
#pragma unroll
    for (int off = 32; off; off >>= 1) {
        s  += __shfl_xor(s, off);
        ss += __shfl_xor(ss, off);
    }
    float mu   = s * (1.0f / 256.0f);
    float var  = ss * (1.0f / 256.0f) - mu * mu;
    float rstd = rsqrtf(fmaxf(var, 0.0f) + 1e-5f);
    const ushort4 gu = *(const ushort4*)((const unsigned short*)g + lane * 4);
    const ushort4 bu = *(const ushort4*)((const unsigned short*)be + lane * 4);
    ushort4 o;
    o.x = f2us((v0 - mu) * rstd * us2f(gu.x) + us2f(bu.x));
    o.y = f2us((v1 - mu) * rstd * us2f(gu.y) + us2f(bu.y));
    o.z = f2us((v2 - mu) * rstd * us2f(gu.z) + us2f(bu.z));
    o.w = f2us((v3 - mu) * rstd * us2f(gu.w) + us2f(bu.w));
    *(ushort4*)(Y + p * 256 + lane * 4) = o;
}

// ---------------------------------------------------------------------------
// Depthwise 3x3 + exact GELU, NHWC (unchanged).
// ---------------------------------------------------------------------------
__global__ __launch_bounds__(256) void dwgelu_nhwc(
    const bf16* __restrict__ H, const bf16* __restrict__ Wr,
    bf16* __restrict__ Y)
{
    int idx = blockIdx.x * 256 + threadIdx.x;
    int p = idx >> 7, c8 = (idx & 127) * 8;
    int hw = p & 1023, hh = hw >> 5, ww = hw & 31;
    size_t ib = ((size_t)(p >> 10)) << 10;
    float acc[8] = {};
#pragma unroll
    for (int kh = 0; kh < 3; ++kh)
#pragma unroll
        for (int kw = 0; kw < 3; ++kw) {
            int hi = hh + kh - 1, wi = ww + kw - 1;
            if ((unsigned)hi < 32u && (unsigned)wi < 32u) {
                v8s hv = *(const v8s*)((const short*)H + (ib + (hi << 5) + wi) * 1024 + c8);
                v8s wvv = *(const v8s*)((const short*)Wr + (kh * 3 + kw) * 1024 + c8);
#pragma unroll
                for (int j = 0; j < 8; ++j)
                    acc[j] = fmaf(us2f((unsigned short)wvv[j]),
                                  us2f((unsigned short)hv[j]), acc[j]);
            }
        }
    short ov[8];
#pragma unroll
    for (int j = 0; j < 8; ++j) {
        float x = acc[j];
        ov[j] = (short)f2us(0.5f * x * (1.0f + erff(x * 0.70710678118654752f)));
    }
    v8s o = {ov[0], ov[1], ov[2], ov[3], ov[4], ov[5], ov[6], ov[7]};
    *(v8s*)((short*)Y + (size_t)p * 1024 + c8) = o;
}

// ---------------------------------------------------------------------------
extern "C" void kernel_launch(void* const* d_in, const int* in_sizes, int n_in,
                              void* d_out, int out_size, void* d_ws, size_t ws_size,
                              hipStream_t stream)
{
    static const int  lidx[20] = {4,5,6,7,8,9,10,11,12,13,14,15,16,17,18,19,20,21,22,24};
    static const unsigned lsz[20] = {256,256,256,256,256,256,256,256,256,256,
                                     196608,65536,196608,65536,
                                     65536,65536,65536,65536,262144,262144};
    CvtArgs args;
    unsigned pre[21]; pre[0] = 0;
    for (int i = 0; i < 20; ++i) {
        args.src[i] = d_in[lidx[i]];
        pre[i + 1] = pre[i] + lsz[i];
    }
    for (int i = 0; i < 21; ++i) args.off[i] = pre[i];
    const unsigned ltot = pre[20];

    int*  flag  = (int*)d_ws;
    bf16* canon = (bf16*)d_ws + 128;
    bf16* cn[25];
    for (int i = 0; i < 20; ++i) cn[lidx[i]] = canon + pre[i];

    bf16* Wr3  = canon + ltot;
    bf16* Wr5  = Wr3 + 589824;
    bf16* Wdwr = Wr5 + 1638400;
    const size_t SZ = 2097152;
    bf16* slab = Wdwr + 9216;
    bf16* qb   = slab + 0 * SZ;                    // q_branch -> x (NHWC)
    bf16* kvb  = slab + 1 * SZ;
    bf16* t0   = slab + 2 * SZ;
    bf16* q    = slab + 3 * SZ;
    bf16* kv   = slab + 4 * SZ;
    bf16* QKb  = slab + 5 * SZ;                    // 2 slots: [8192][512]
    bf16* Vb   = slab + 7 * SZ;                    // 1 slot: CHW [8][256][1024]
    bf16* hb   = slab + 5 * SZ;                    // 4 slots (QKb/Vb dead)
    bf16* h2   = slab + 1 * SZ;                    // 4 slots (kvb..kv dead)
    bf16* aopT = kvb;
    bf16* dopT = t0;
    float* out = (float*)d_out;

    dim3 blk(256);
    auto S = [](const bf16* p) { return (const short*)p; };

    detect_kernel<<<1, 64, 0, stream>>>((const unsigned short*)d_in[4], flag);
    cvt_lin<<<ltot / 256, blk, 0, stream>>>(args, flag, canon);
    tcvt<<<dim3(16, 4, 8), blk, 0, stream>>>(d_in[0], flag, aopT);
    tcvt<<<dim3(16, 4, 8), blk, 0, stream>>>(d_in[1], flag, dopT);
    repack_conv<3><<<2304, blk, 0, stream>>>(d_in[2], flag, Wr3);
    repack_conv<5><<<6400, blk, 0, stream>>>(d_in[3], flag, Wr5);
    repack_dw<<<36, blk, 0, stream>>>(d_in[23], flag, Wdwr);

    // branches
    mconv<3, 1><<<dim3(128, 4), blk, 0, stream>>>(S(aopT), (const short*)Wr3, qb);
    mconv<5, 2><<<dim3(128, 4), blk, 0, stream>>>(S(dopT), (const short*)Wr5, kvb);

    // q-branch self-attention
    ln_nhwc<<<2048, blk, 0, stream>>>(qb, cn[4], cn[5], t0);
    mgemm<<<dim3(12, 128), blk, 0, stream>>>(S(cn[14]), S(t0), QKb, nullptr, Vb, nullptr, 256, 3, 0);
    attn_mfma<<<dim3(16, 4, 8), blk, 0, stream>>>(QKb, Vb, t0);
    mgemm<<<dim3(128, 4), blk, 0, stream>>>(S(t0), S(cn[15]), qb, nullptr, nullptr, qb, 256, 0, 256);
    ln_nhwc<<<2048, blk, 0, stream>>>(qb, cn[8], cn[9], q);

    // kv-branch self-attention
    ln_nhwc<<<2048, blk, 0, stream>>>(kvb, cn[6], cn[7], t0);
    mgemm<<<dim3(12, 128), blk, 0, stream>>>(S(cn[16]), S(t0), QKb, nullptr, Vb, nullptr, 256, 3, 0);
    attn_mfma<<<dim3(16, 4, 8), blk, 0, stream>>>(QKb, Vb, t0);
    mgemm<<<dim3(128, 4), blk, 0, stream>>>(S(t0), S(cn[17]), kvb, nullptr, nullptr, kvb, 256, 0, 256);
    ln_nhwc<<<2048, blk, 0, stream>>>(kvb, cn[10], cn[11], kv);

    // cross attention
    mgemm<<<dim3(4, 128), blk, 0, stream>>>(S(cn[18]), S(q),  QKb, nullptr, nullptr, nullptr, 256, 4, 0);
    mgemm<<<dim3(4, 128), blk, 0, stream>>>(S(cn[19]), S(kv), QKb, nullptr, nullptr, nullptr, 256, 4, 256);
    mgemm<<<dim3(4, 128), blk, 0, stream>>>(S(cn[20]), S(kv), Vb,  nullptr, nullptr, nullptr, 256, 1, 256);
    attn_mfma<<<dim3(16, 4, 8), blk, 0, stream>>>(QKb, Vb, t0);
    mgemm<<<dim3(128, 4), blk, 0, stream>>>(S(t0), S(cn[21]), qb, nullptr, nullptr, qb, 256, 0, 256);

    // LeFF
    ln_nhwc<<<2048, blk, 0, stream>>>(qb, cn[12], cn[13], t0);
    mgemm<<<dim3(128, 16), blk, 0, stream>>>(S(t0), S(cn[22]), hb, nullptr, nullptr, nullptr, 256, 0, 1024);
    dwgelu_nhwc<<<4096, blk, 0, stream>>>(hb, Wdwr, h2);
    mgemm<<<dim3(4, 128), blk, 0, stream>>>(S(cn[24]), S(h2), nullptr, out, nullptr, qb, 1024, 2, 256);
}